// Round 5
// baseline (6466.910 us; speedup 1.0000x reference)
//
#include <hip/hip_runtime.h>
#include <hip/hip_bf16.h>

#define H 1024
#define B3H 3072
#define BATCH 128
#define TSTEPS 256
#define LROW 520                 // 512 k-chunk + 8 pad (shorts)
#define PLANE (16 * LROW)        // one 16-row bf16 plane per chunk
#define NBLK 256
#define NTHR 768                 // 12 waves: (gate, n-half)

typedef __attribute__((ext_vector_type(8))) short short8;
typedef __attribute__((ext_vector_type(4))) float f32x4;

static __device__ __forceinline__ float bf2f(__hip_bfloat16 v) { return __bfloat162float(v); }
static __device__ __forceinline__ unsigned short f2bf_bits(float f) {
    __hip_bfloat16 h = __float2bfloat16(f);
    return __builtin_bit_cast(unsigned short, h);
}
static __device__ __forceinline__ float bits2f(unsigned short b) {
    return bf2f(__builtin_bit_cast(__hip_bfloat16, b));
}
static __device__ __forceinline__ unsigned short bfbits(__hip_bfloat16 v) {
    return __builtin_bit_cast(unsigned short, v);
}
static __device__ __forceinline__ void split_bf(float v, unsigned short& hi, unsigned short& lo) {
    hi = f2bf_bits(v);
    lo = f2bf_bits(v - bits2f(hi));
}

// ws layout
#define BAR_OFF  128                       // 256 arrival slots (u32), 1 KB
#define PW_OFF   2048
#define PWL_OFF  (PW_OFF + 12582912)
#define XHI_OFF  (PWL_OFF + 12582912)
#define XLO_OFF  (XHI_OFF + 262144)
#define H0HI_OFF (XLO_OFF + 262144)
#define H0LO_OFF (H0HI_OFF + 262144)
#define H1HI_OFF (H0LO_OFF + 262144)
#define H1LO_OFF (H1HI_OFF + 262144)

__global__ void detect_dtype(const unsigned int* __restrict__ w, int* __restrict__ flag) {
    __shared__ int cnt[256];
    int c = 0;
    for (int i = threadIdx.x; i < 4096; i += 256) {
        unsigned int v = (w[i] >> 8) & 0x7f;
        c += (v >= 0x33 && v <= 0x3f) ? 1 : 0;
    }
    cnt[threadIdx.x] = c;
    __syncthreads();
    for (int s = 128; s > 0; s >>= 1) {
        if (threadIdx.x < s) cnt[threadIdx.x] += cnt[threadIdx.x + s];
        __syncthreads();
    }
    if (threadIdx.x == 0) *flag = (cnt[0] * 2 > 4096) ? 1 : 0;
}

// Pack W into MFMA B-fragment layout, bf16 hi/lo pair (unchanged — verified).
__global__ void pack_w(const void* __restrict__ Kp, const void* __restrict__ Rp,
                       __hip_bfloat16* __restrict__ pwh, __hip_bfloat16* __restrict__ pwl,
                       const int* __restrict__ flag) {
    int idx = blockIdx.x * 256 + threadIdx.x;
    int lane = idx & 63;
    int kc   = (idx >> 6) & 31;
    int ns   = (idx >> 11) & 1;
    int it   = (idx >> 12) & 31;
    int g    = idx >> 17;
    if (g >= 6) return;
    const int isbf = *flag;
    int col   = (g % 3) * 1024 + it * 32 + ns * 16 + (lane & 15);
    int kbase = kc * 32 + (lane >> 4) * 8;
    unsigned short eh[8], el[8];
    if (isbf) {
        const __hip_bfloat16* src = (const __hip_bfloat16*)((g < 3) ? Kp : Rp);
#pragma unroll
        for (int j = 0; j < 8; ++j) { eh[j] = bfbits(src[(size_t)(kbase + j) * B3H + col]); el[j] = 0; }
    } else {
        const float* src = (const float*)((g < 3) ? Kp : Rp);
#pragma unroll
        for (int j = 0; j < 8; ++j) split_bf(src[(size_t)(kbase + j) * B3H + col], eh[j], el[j]);
    }
    uint4 vh, vl;
    vh.x = (unsigned int)eh[0] | ((unsigned int)eh[1] << 16);
    vh.y = (unsigned int)eh[2] | ((unsigned int)eh[3] << 16);
    vh.z = (unsigned int)eh[4] | ((unsigned int)eh[5] << 16);
    vh.w = (unsigned int)eh[6] | ((unsigned int)eh[7] << 16);
    vl.x = (unsigned int)el[0] | ((unsigned int)el[1] << 16);
    vl.y = (unsigned int)el[2] | ((unsigned int)el[3] << 16);
    vl.z = (unsigned int)el[4] | ((unsigned int)el[5] << 16);
    vl.w = (unsigned int)el[6] | ((unsigned int)el[7] << 16);
    *(uint4*)(pwh + (size_t)idx * 8) = vh;
    *(uint4*)(pwl + (size_t)idx * 8) = vl;
}

// Inputs -> pre-split bf16 hi/lo planes. Also zeroes the arrival slots.
__global__ void init_bufs(const void* __restrict__ cin, const void* __restrict__ hs,
                          unsigned short* __restrict__ xhi, unsigned short* __restrict__ xlo,
                          unsigned short* __restrict__ hhi, unsigned short* __restrict__ hlo,
                          unsigned int* __restrict__ bar,
                          const int* __restrict__ flag) {
    int i = blockIdx.x * 256 + threadIdx.x;
    if (blockIdx.x == 0 && threadIdx.x < 480) bar[threadIdx.x] = 0;
    if (i >= BATCH * H) return;
    float xv, hv;
    if (*flag) {
        xv = bf2f(((const __hip_bfloat16*)cin)[i]);
        hv = bf2f(((const __hip_bfloat16*)hs)[i]);
    } else {
        xv = ((const float*)cin)[i];
        hv = ((const float*)hs)[i];
    }
    unsigned short a, b;
    split_bf(xv, a, b); xhi[i] = a; xlo[i] = b;
    split_bf(hv, a, b); hhi[i] = a; hlo[i] = b;
}

// ---------------------------------------------------------------------------
// Persistent GRU. R5 = R4 GEMM core (12 waves, lockstep) with the two serial
// latencies fixed:
//  (1) arrival-ARRAY barrier: block b sc1-stores (t+1) to its own slot; wave0
//      polls all 256 slots (4 sc1 loads/lane + __all). Replaces 256 serialized
//      fetch_adds on ONE MALL line contended by 256 spinners (R2/R4's hidden
//      cost). Still a full grid barrier -> lockstep L2 co-timing preserved.
//  (2) batched reg staging (R3's good half): all sc1 h-loads issued into regs
//      back-to-back (one MALL latency exposure), then written to LDS. Weight
//      warm-up loads hoisted above staging to overlap.
// ---------------------------------------------------------------------------
__launch_bounds__(NTHR, 1)
__global__ void gru_persistent(const unsigned short* __restrict__ xhi,
                               const unsigned short* __restrict__ xlo,
                               unsigned short* __restrict__ h0hi,
                               unsigned short* __restrict__ h0lo,
                               unsigned short* __restrict__ h1hi,
                               unsigned short* __restrict__ h1lo,
                               const __hip_bfloat16* __restrict__ pwh,
                               const __hip_bfloat16* __restrict__ pwl,
                               const void* __restrict__ bias,
                               void* __restrict__ out,
                               unsigned int* __restrict__ bar,
                               const int* __restrict__ flag) {
    // t=0 planes: [Ahi][Alo][Bhi][Blo] of chunk c; t>=1: [c0hi][c0lo][c1hi][c1lo]
    __shared__ unsigned short sA[4 * PLANE];  // 66560 B (aliased as sG fp32 post-GEMM)
    __shared__ float sHold[512];              // this block's h tile, full f32
    __shared__ float sBias[192];              // 6 gates x 32 cols

    const int tid  = threadIdx.x;
    const int w    = tid >> 6;        // wave 0..11
    const int g    = w >> 1;          // gate 0..5
    const int half = w & 1;           // n-half 0..1
    const int lane = tid & 63;
    const int bt = blockIdx.x >> 5;   // 0..7, 16-row tiles
    const int it = blockIdx.x & 31;   // 0..31, 32-col slices
    const int bbase = bt * 16;
    const int m0 = lane & 15;
    const int q  = lane >> 4;
    const int aoffm = m0 * LROW;
    const int ibase0 = it * 32;
    const int isbf = *flag;

    // preload bias once
    {
        const __hip_bfloat16* bias_b = (const __hip_bfloat16*)bias;
        const float* bias_f = (const float*)bias;
        for (int e = tid; e < 192; e += NTHR) {
            int gg = e >> 5;
            int i  = ibase0 + (e & 31);
            int src = (gg < 3) ? (gg * 1024 + i) : (B3H + (gg - 3) * 1024 + i);
            sBias[e] = isbf ? bf2f(bias_b[src]) : bias_f[src];
        }
    }

    // this wave's single weight stream pair (16 cols)
    const size_t boff = ((size_t)((g * 32 + it) * 2 + half) * 32) * 64 + lane;
    const uint4* bh = (const uint4*)pwh + boff;
    const uint4* bl = (const uint4*)pwl + boff;

    __hip_bfloat16* outb = (__hip_bfloat16*)out;
    float* outf = (float*)out;

    for (int t = 0; t < TSTEPS; ++t) {
        const int cur = t & 1;
        const unsigned short* curhi = cur ? h1hi : h0hi;
        const unsigned short* curlo = cur ? h1lo : h0lo;
        unsigned short* dsthi = cur ? h0hi : h1hi;
        unsigned short* dstlo = cur ? h0lo : h1lo;

        f32x4 acc = {0.f, 0.f, 0.f, 0.f};

        if (t == 0) {
            // ---- t=0 (once): x (gates 0-2) + h0 (gates 3-5), cached loads ----
            const unsigned short* aH0 = sA + ((g < 3) ? 0 : 2) * PLANE;
            const unsigned short* aL0 = aH0 + PLANE;
            for (int c = 0; c < 2; ++c) {
                if (c) __syncthreads();
                const int kstart = c * 512;
                for (int g4 = tid; g4 < 4096; g4 += NTHR) {
                    int plane = g4 >> 10;
                    int rem   = g4 & 1023;
                    int row   = rem >> 6;
                    int kg    = rem & 63;
                    const unsigned short* src =
                        (plane == 0) ? xhi : (plane == 1) ? xlo : (plane == 2) ? curhi : curlo;
                    uint4 v = *(const uint4*)&src[(size_t)(bbase + row) * H + kstart + kg * 8];
                    *(uint4*)&sA[plane * PLANE + row * LROW + kg * 8] = v;
                }
                __syncthreads();
#pragma unroll 4
                for (int kc = 0; kc < 16; ++kc) {
                    const int kcg = c * 16 + kc;
                    short8 Bh = __builtin_bit_cast(short8, bh[(size_t)kcg * 64]);
                    short8 Bl = __builtin_bit_cast(short8, bl[(size_t)kcg * 64]);
                    const int koff = kc * 32 + q * 8;
                    short8 a_h = *(const short8*)&aH0[aoffm + koff];
                    short8 a_l = *(const short8*)&aL0[aoffm + koff];
                    acc = __builtin_amdgcn_mfma_f32_16x16x32_bf16(a_h, Bh, acc, 0, 0, 0);
                    acc = __builtin_amdgcn_mfma_f32_16x16x32_bf16(a_h, Bl, acc, 0, 0, 0);
                    acc = __builtin_amdgcn_mfma_f32_16x16x32_bf16(a_l, Bh, acc, 0, 0, 0);
                }
            }
        } else {
            // ---- t>=1: weight warm-up first (L2 hits, overlap with staging) ----
            uint4 wph[4], wpl[4];
#pragma unroll
            for (int p = 0; p < 4; ++p) {
                wph[p] = bh[(size_t)p * 64];
                wpl[p] = bl[(size_t)p * 64];
            }

            // ---- batched sc1 h staging: regs first (one latency exposure) ----
            // planes: 0=c0hi 1=c0lo 2=c1hi 3=c1lo; granule = u64 (4 shorts)
            // 8192 granules = 768*10 + 512 tail
            unsigned long long hv[10];
#pragma unroll
            for (int r2 = 0; r2 < 10; ++r2) {
                int g4 = tid + r2 * NTHR;
                int plane = g4 >> 11;
                int rem   = g4 & 2047;
                int row   = rem >> 7;
                int kg    = rem & 127;
                const unsigned short* src = (plane & 1) ? curlo : curhi;
                const unsigned long long* p = (const unsigned long long*)
                    &src[(size_t)(bbase + row) * H + (plane >> 1) * 512 + kg * 4];
                hv[r2] = __hip_atomic_load(p, __ATOMIC_RELAXED, __HIP_MEMORY_SCOPE_AGENT);
            }
            unsigned long long tl = 0;
            if (tid < 512) {
                int g4 = 7680 + tid;               // plane = 3 always
                int rem = g4 & 2047;
                int row = rem >> 7;
                int kg  = rem & 127;
                const unsigned long long* p = (const unsigned long long*)
                    &curlo[(size_t)(bbase + row) * H + 512 + kg * 4];
                tl = __hip_atomic_load(p, __ATOMIC_RELAXED, __HIP_MEMORY_SCOPE_AGENT);
            }
#pragma unroll
            for (int r2 = 0; r2 < 10; ++r2) {
                int g4 = tid + r2 * NTHR;
                int plane = g4 >> 11;
                int rem   = g4 & 2047;
                int row   = rem >> 7;
                int kg    = rem & 127;
                *(unsigned long long*)&sA[plane * PLANE + row * LROW + kg * 4] = hv[r2];
            }
            if (tid < 512) {
                int g4 = 7680 + tid;
                int rem = g4 & 2047;
                int row = rem >> 7;
                int kg  = rem & 127;
                *(unsigned long long*)&sA[3 * PLANE + row * LROW + kg * 4] = tl;
            }
            __syncthreads();

            // ---- fused 32-kcg loop: depth-4 weight pipeline, depth-2 A pipeline ----
            short8 pa_h[2], pa_l[2];
            pa_h[0] = *(const short8*)&sA[aoffm + q * 8];
            pa_l[0] = *(const short8*)&sA[PLANE + aoffm + q * 8];
#pragma unroll
            for (int kcg = 0; kcg < 32; ++kcg) {
                const int s = kcg & 3;
                if (kcg + 1 < 32) {
                    const int kn   = kcg + 1;
                    const int base = (kn >> 4) * 2 * PLANE;
                    const int koff = (kn & 15) * 32 + q * 8;
                    pa_h[kn & 1] = *(const short8*)&sA[base + aoffm + koff];
                    pa_l[kn & 1] = *(const short8*)&sA[base + PLANE + aoffm + koff];
                }
                short8 Bh = __builtin_bit_cast(short8, wph[s]);
                short8 Bl = __builtin_bit_cast(short8, wpl[s]);
                if (kcg + 4 < 32) {
                    wph[s] = bh[(size_t)(kcg + 4) * 64];
                    wpl[s] = bl[(size_t)(kcg + 4) * 64];
                }
                const short8 a_h = pa_h[kcg & 1];
                const short8 a_l = pa_l[kcg & 1];
                acc = __builtin_amdgcn_mfma_f32_16x16x32_bf16(a_h, Bh, acc, 0, 0, 0);
                acc = __builtin_amdgcn_mfma_f32_16x16x32_bf16(a_h, Bl, acc, 0, 0, 0);
                acc = __builtin_amdgcn_mfma_f32_16x16x32_bf16(a_l, Bh, acc, 0, 0, 0);
            }
        }

        __syncthreads();
        float* sG = (float*)sA;  // 6 gate planes [16 x 32] fp32 (12 KB, aliases sA)
        {
            // C/D layout: col = lane&15, row = (lane>>4)*4 + reg  [m89/m91 verified]
#pragma unroll
            for (int r = 0; r < 4; ++r) {
                int mrow = q * 4 + r;
                sG[g * 512 + mrow * 32 + m0 + half * 16] = acc[r];
            }
        }
        __syncthreads();

        // epilogue: 256 threads x 2 adjacent elements (packed u32 h' stores)
        if (tid < 256) {
            const int e0   = tid * 2;
            const int mloc = e0 >> 5;
            const int b    = bbase + mloc;
            const int i0   = ibase0 + (e0 & 31);
            const size_t hidx0 = (size_t)b * H + i0;
            float hn[2];
            unsigned short nh[2], nl[2];
#pragma unroll
            for (int j = 0; j < 2; ++j) {
                const int e = e0 + j;
                const int nloc = e & 31;
                float xz = sG[e], xr = sG[512 + e], xh = sG[1024 + e];
                float hz = sG[1536 + e], hr = sG[2048 + e], hh = sG[2560 + e];
                float zlin = xz + sBias[nloc]      + hz + sBias[96 + nloc];
                float rlin = xr + sBias[32 + nloc] + hr + sBias[128 + nloc];
                float xht  = xh + sBias[64 + nloc];
                float hht  = hh + sBias[160 + nloc];   // recurrent bias INSIDE r*(...)
                float z  = 1.0f / (1.0f + expf(-zlin));
                float r  = 1.0f / (1.0f + expf(-rlin));
                float hc = tanhf(xht + r * hht);
                float hold = t ? sHold[e]
                               : (bits2f(curhi[hidx0 + j]) + bits2f(curlo[hidx0 + j]));
                float hnew = z * hold + (1.0f - z) * hc;
                sHold[e] = hnew;
                hn[j] = hnew;
                split_bf(hnew, nh[j], nl[j]);
            }
            if (t < TSTEPS - 1) {
                unsigned int hiw = (unsigned int)nh[0] | ((unsigned int)nh[1] << 16);
                unsigned int low = (unsigned int)nl[0] | ((unsigned int)nl[1] << 16);
                __hip_atomic_store((unsigned int*)&dsthi[hidx0], hiw,
                                   __ATOMIC_RELAXED, __HIP_MEMORY_SCOPE_AGENT);
                __hip_atomic_store((unsigned int*)&dstlo[hidx0], low,
                                   __ATOMIC_RELAXED, __HIP_MEMORY_SCOPE_AGENT);
            }
            const size_t o1 = (size_t)b * (TSTEPS * H) + (size_t)t * H + i0;
            if (isbf) {
                outb[o1]     = __float2bfloat16(hn[0]);
                outb[o1 + 1] = __float2bfloat16(hn[1]);
                if (t == TSTEPS - 1) {
                    outb[(size_t)BATCH * TSTEPS * H + hidx0]     = __float2bfloat16(hn[0]);
                    outb[(size_t)BATCH * TSTEPS * H + hidx0 + 1] = __float2bfloat16(hn[1]);
                }
            } else {
                outf[o1]     = hn[0];
                outf[o1 + 1] = hn[1];
                if (t == TSTEPS - 1) {
                    outf[(size_t)BATCH * TSTEPS * H + hidx0]     = hn[0];
                    outf[(size_t)BATCH * TSTEPS * H + hidx0 + 1] = hn[1];
                }
            }
        }

        // ---- arrival-array lockstep barrier (no RMW, no shared hot write-line) ----
        if (t < TSTEPS - 1) {
            asm volatile("s_waitcnt vmcnt(0)" ::: "memory");  // own h' stores acked
            __syncthreads();
            if (tid == 0) {
                __hip_atomic_store(&bar[blockIdx.x], (unsigned int)(t + 1),
                                   __ATOMIC_RELAXED, __HIP_MEMORY_SCOPE_AGENT);
            }
            if (w == 0) {
                const unsigned int target = (unsigned int)(t + 1);
                for (;;) {
                    unsigned int v0 = __hip_atomic_load(&bar[lane],
                                        __ATOMIC_RELAXED, __HIP_MEMORY_SCOPE_AGENT);
                    unsigned int v1 = __hip_atomic_load(&bar[lane + 64],
                                        __ATOMIC_RELAXED, __HIP_MEMORY_SCOPE_AGENT);
                    unsigned int v2 = __hip_atomic_load(&bar[lane + 128],
                                        __ATOMIC_RELAXED, __HIP_MEMORY_SCOPE_AGENT);
                    unsigned int v3 = __hip_atomic_load(&bar[lane + 192],
                                        __ATOMIC_RELAXED, __HIP_MEMORY_SCOPE_AGENT);
                    int ok = (v0 >= target) && (v1 >= target) &&
                             (v2 >= target) && (v3 >= target);
                    if (__all(ok)) break;
                    __builtin_amdgcn_s_sleep(1);
                }
            }
            __syncthreads();
        }
    }
}

extern "C" void kernel_launch(void* const* d_in, const int* in_sizes, int n_in,
                              void* d_out, int out_size, void* d_ws, size_t ws_size,
                              hipStream_t stream) {
    const void* cin  = d_in[0];
    const void* hs   = d_in[1];
    const void* Kw   = d_in[2];
    const void* Rw   = d_in[3];
    const void* bias = d_in[4];

    char* ws = (char*)d_ws;
    int* flag = (int*)ws;
    unsigned int* bar = (unsigned int*)(ws + BAR_OFF);
    __hip_bfloat16* pwh = (__hip_bfloat16*)(ws + PW_OFF);
    __hip_bfloat16* pwl = (__hip_bfloat16*)(ws + PWL_OFF);
    unsigned short* xhi  = (unsigned short*)(ws + XHI_OFF);
    unsigned short* xlo  = (unsigned short*)(ws + XLO_OFF);
    unsigned short* h0hi = (unsigned short*)(ws + H0HI_OFF);
    unsigned short* h0lo = (unsigned short*)(ws + H0LO_OFF);
    unsigned short* h1hi = (unsigned short*)(ws + H1HI_OFF);
    unsigned short* h1lo = (unsigned short*)(ws + H1LO_OFF);

    detect_dtype<<<1, 256, 0, stream>>>((const unsigned int*)Kw, flag);
    pack_w<<<3072, 256, 0, stream>>>(Kw, Rw, pwh, pwl, flag);
    init_bufs<<<512, 256, 0, stream>>>(cin, hs, xhi, xlo, h0hi, h0lo, bar, flag);

    const unsigned short* xhi_c = xhi;
    const unsigned short* xlo_c = xlo;
    const __hip_bfloat16* pwh_c = pwh;
    const __hip_bfloat16* pwl_c = pwl;
    const int* flag_c = flag;
    void* kargs[] = {
        (void*)&xhi_c, (void*)&xlo_c,
        (void*)&h0hi, (void*)&h0lo, (void*)&h1hi, (void*)&h1lo,
        (void*)&pwh_c, (void*)&pwl_c,
        (void*)&bias, (void*)&d_out, (void*)&bar, (void*)&flag_c
    };
    hipLaunchCooperativeKernel((void*)gru_persistent, dim3(256), dim3(NTHR),
                               kargs, 0, stream);
}

// Round 6
// 5606.917 us; speedup vs baseline: 1.1534x; 1.1534x over previous
//
#include <hip/hip_runtime.h>
#include <hip/hip_bf16.h>

#define H 1024
#define B3H 3072
#define BATCH 128
#define TSTEPS 256
#define LROW 520                 // 512 k-chunk + 8 pad (shorts)
#define PLANE (16 * LROW)        // one 16-row bf16 plane per chunk
#define NBLK 256
#define NTHR 768                 // 12 waves: (gate, n-half)

typedef __attribute__((ext_vector_type(8))) short short8;
typedef __attribute__((ext_vector_type(4))) float f32x4;

static __device__ __forceinline__ float bf2f(__hip_bfloat16 v) { return __bfloat162float(v); }
static __device__ __forceinline__ unsigned short f2bf_bits(float f) {
    __hip_bfloat16 h = __float2bfloat16(f);
    return __builtin_bit_cast(unsigned short, h);
}
static __device__ __forceinline__ float bits2f(unsigned short b) {
    return bf2f(__builtin_bit_cast(__hip_bfloat16, b));
}
static __device__ __forceinline__ unsigned short bfbits(__hip_bfloat16 v) {
    return __builtin_bit_cast(unsigned short, v);
}
static __device__ __forceinline__ void split_bf(float v, unsigned short& hi, unsigned short& lo) {
    hi = f2bf_bits(v);
    lo = f2bf_bits(v - bits2f(hi));
}

// ws layout
#define BAR_OFF  128
#define PW_OFF   2048
#define PWL_OFF  (PW_OFF + 12582912)
#define XHI_OFF  (PWL_OFF + 12582912)
#define XLO_OFF  (XHI_OFF + 262144)
#define H0HI_OFF (XLO_OFF + 262144)
#define H0LO_OFF (H0HI_OFF + 262144)
#define H1HI_OFF (H0LO_OFF + 262144)
#define H1LO_OFF (H1HI_OFF + 262144)

__global__ void detect_dtype(const unsigned int* __restrict__ w, int* __restrict__ flag) {
    __shared__ int cnt[256];
    int c = 0;
    for (int i = threadIdx.x; i < 4096; i += 256) {
        unsigned int v = (w[i] >> 8) & 0x7f;
        c += (v >= 0x33 && v <= 0x3f) ? 1 : 0;
    }
    cnt[threadIdx.x] = c;
    __syncthreads();
    for (int s = 128; s > 0; s >>= 1) {
        if (threadIdx.x < s) cnt[threadIdx.x] += cnt[threadIdx.x + s];
        __syncthreads();
    }
    if (threadIdx.x == 0) *flag = (cnt[0] * 2 > 4096) ? 1 : 0;
}

// Pack W into MFMA B-fragment layout, bf16 hi/lo pair (unchanged — verified).
__global__ void pack_w(const void* __restrict__ Kp, const void* __restrict__ Rp,
                       __hip_bfloat16* __restrict__ pwh, __hip_bfloat16* __restrict__ pwl,
                       const int* __restrict__ flag) {
    int idx = blockIdx.x * 256 + threadIdx.x;
    int lane = idx & 63;
    int kc   = (idx >> 6) & 31;
    int ns   = (idx >> 11) & 1;
    int it   = (idx >> 12) & 31;
    int g    = idx >> 17;
    if (g >= 6) return;
    const int isbf = *flag;
    int col   = (g % 3) * 1024 + it * 32 + ns * 16 + (lane & 15);
    int kbase = kc * 32 + (lane >> 4) * 8;
    unsigned short eh[8], el[8];
    if (isbf) {
        const __hip_bfloat16* src = (const __hip_bfloat16*)((g < 3) ? Kp : Rp);
#pragma unroll
        for (int j = 0; j < 8; ++j) { eh[j] = bfbits(src[(size_t)(kbase + j) * B3H + col]); el[j] = 0; }
    } else {
        const float* src = (const float*)((g < 3) ? Kp : Rp);
#pragma unroll
        for (int j = 0; j < 8; ++j) split_bf(src[(size_t)(kbase + j) * B3H + col], eh[j], el[j]);
    }
    uint4 vh, vl;
    vh.x = (unsigned int)eh[0] | ((unsigned int)eh[1] << 16);
    vh.y = (unsigned int)eh[2] | ((unsigned int)eh[3] << 16);
    vh.z = (unsigned int)eh[4] | ((unsigned int)eh[5] << 16);
    vh.w = (unsigned int)eh[6] | ((unsigned int)eh[7] << 16);
    vl.x = (unsigned int)el[0] | ((unsigned int)el[1] << 16);
    vl.y = (unsigned int)el[2] | ((unsigned int)el[3] << 16);
    vl.z = (unsigned int)el[4] | ((unsigned int)el[5] << 16);
    vl.w = (unsigned int)el[6] | ((unsigned int)el[7] << 16);
    *(uint4*)(pwh + (size_t)idx * 8) = vh;
    *(uint4*)(pwl + (size_t)idx * 8) = vl;
}

// Inputs -> pre-split bf16 hi/lo planes. Also zeroes the barrier counter.
__global__ void init_bufs(const void* __restrict__ cin, const void* __restrict__ hs,
                          unsigned short* __restrict__ xhi, unsigned short* __restrict__ xlo,
                          unsigned short* __restrict__ hhi, unsigned short* __restrict__ hlo,
                          unsigned int* __restrict__ bar,
                          const int* __restrict__ flag) {
    int i = blockIdx.x * 256 + threadIdx.x;
    if (blockIdx.x == 0 && threadIdx.x < 480) bar[threadIdx.x] = 0;
    if (i >= BATCH * H) return;
    float xv, hv;
    if (*flag) {
        xv = bf2f(((const __hip_bfloat16*)cin)[i]);
        hv = bf2f(((const __hip_bfloat16*)hs)[i]);
    } else {
        xv = ((const float*)cin)[i];
        hv = ((const float*)hs)[i];
    }
    unsigned short a, b;
    split_bf(xv, a, b); xhi[i] = a; xlo[i] = b;
    split_bf(hv, a, b); hhi[i] = a; hlo[i] = b;
}

// ---------------------------------------------------------------------------
// Persistent GRU. R6 = R4 (best: 5824 µs) with ONE change: the h staging.
// R4 staged h via per-iteration relaxed ATOMIC u64 loads — serialized
// (~11 device-coherent round trips/thread ≈ 9 µs/step of exposed latency).
// Batching ATOMIC loads (R3/R5) tripled FETCH_SIZE (34 MB/step) — atomic
// many-outstanding requests appear to defeat line merging. R6 batches via
// NON-atomic `global_load_dwordx4 ... sc0 sc1` in a single asm block (5
// loads, one s_waitcnt inside): same coherence point (MALL), normal VMEM
// miss path -> mergeable, ONE latency exposure.
// ---------------------------------------------------------------------------
__launch_bounds__(NTHR, 1)
__global__ void gru_persistent(const unsigned short* __restrict__ xhi,
                               const unsigned short* __restrict__ xlo,
                               unsigned short* __restrict__ h0hi,
                               unsigned short* __restrict__ h0lo,
                               unsigned short* __restrict__ h1hi,
                               unsigned short* __restrict__ h1lo,
                               const __hip_bfloat16* __restrict__ pwh,
                               const __hip_bfloat16* __restrict__ pwl,
                               const void* __restrict__ bias,
                               void* __restrict__ out,
                               unsigned int* __restrict__ bar,
                               const int* __restrict__ flag) {
    // t=0 planes: [Ahi][Alo][Bhi][Blo] of chunk c; t>=1: [c0hi][c0lo][c1hi][c1lo]
    __shared__ unsigned short sA[4 * PLANE];  // 66560 B (aliased as sG fp32 post-GEMM)
    __shared__ float sHold[512];              // this block's h tile, full f32
    __shared__ float sBias[192];              // 6 gates x 32 cols

    const int tid  = threadIdx.x;
    const int w    = tid >> 6;        // wave 0..11
    const int g    = w >> 1;          // gate 0..5
    const int half = w & 1;           // n-half 0..1
    const int lane = tid & 63;
    const int bt = blockIdx.x >> 5;   // 0..7, 16-row tiles
    const int it = blockIdx.x & 31;   // 0..31, 32-col slices
    const int bbase = bt * 16;
    const int m0 = lane & 15;
    const int q  = lane >> 4;
    const int aoffm = m0 * LROW;
    const int ibase0 = it * 32;
    const int isbf = *flag;

    // preload bias once
    {
        const __hip_bfloat16* bias_b = (const __hip_bfloat16*)bias;
        const float* bias_f = (const float*)bias;
        for (int e = tid; e < 192; e += NTHR) {
            int gg = e >> 5;
            int i  = ibase0 + (e & 31);
            int src = (gg < 3) ? (gg * 1024 + i) : (B3H + (gg - 3) * 1024 + i);
            sBias[e] = isbf ? bf2f(bias_b[src]) : bias_f[src];
        }
    }

    // this wave's single weight stream pair (16 cols)
    const size_t boff = ((size_t)((g * 32 + it) * 2 + half) * 32) * 64 + lane;
    const uint4* bh = (const uint4*)pwh + boff;
    const uint4* bl = (const uint4*)pwl + boff;

    __hip_bfloat16* outb = (__hip_bfloat16*)out;
    float* outf = (float*)out;

    for (int t = 0; t < TSTEPS; ++t) {
        const int cur = t & 1;
        const unsigned short* curhi = cur ? h1hi : h0hi;
        const unsigned short* curlo = cur ? h1lo : h0lo;
        unsigned short* dsthi = cur ? h0hi : h1hi;
        unsigned short* dstlo = cur ? h0lo : h1lo;

        f32x4 acc = {0.f, 0.f, 0.f, 0.f};

        if (t == 0) {
            // ---- t=0 (once): x (gates 0-2) + h0 (gates 3-5), cached loads ----
            const unsigned short* aH0 = sA + ((g < 3) ? 0 : 2) * PLANE;
            const unsigned short* aL0 = aH0 + PLANE;
            for (int c = 0; c < 2; ++c) {
                if (c) __syncthreads();
                const int kstart = c * 512;
                for (int g4 = tid; g4 < 4096; g4 += NTHR) {
                    int plane = g4 >> 10;
                    int rem   = g4 & 1023;
                    int row   = rem >> 6;
                    int kg    = rem & 63;
                    const unsigned short* src =
                        (plane == 0) ? xhi : (plane == 1) ? xlo : (plane == 2) ? curhi : curlo;
                    uint4 v = *(const uint4*)&src[(size_t)(bbase + row) * H + kstart + kg * 8];
                    *(uint4*)&sA[plane * PLANE + row * LROW + kg * 8] = v;
                }
                __syncthreads();
#pragma unroll 4
                for (int kc = 0; kc < 16; ++kc) {
                    const int kcg = c * 16 + kc;
                    short8 Bh = __builtin_bit_cast(short8, bh[(size_t)kcg * 64]);
                    short8 Bl = __builtin_bit_cast(short8, bl[(size_t)kcg * 64]);
                    const int koff = kc * 32 + q * 8;
                    short8 a_h = *(const short8*)&aH0[aoffm + koff];
                    short8 a_l = *(const short8*)&aL0[aoffm + koff];
                    acc = __builtin_amdgcn_mfma_f32_16x16x32_bf16(a_h, Bh, acc, 0, 0, 0);
                    acc = __builtin_amdgcn_mfma_f32_16x16x32_bf16(a_h, Bl, acc, 0, 0, 0);
                    acc = __builtin_amdgcn_mfma_f32_16x16x32_bf16(a_l, Bh, acc, 0, 0, 0);
                }
            }
        } else {
            // ---- t>=1: batched device-coherent staging, NON-atomic path ----
            // 4096 x 16B granules: planes 0=c0hi 1=c0lo 2=c1hi 3=c1lo,
            // each plane = 16 rows x 64 granules. gi = r2*NTHR + tid.
            const unsigned short* gp[5];
            int ld[5];
#pragma unroll
            for (int r2 = 0; r2 < 5; ++r2) {
                int gi = r2 * NTHR + tid;
                int plane = gi >> 10;
                int rem   = gi & 1023;
                int row   = rem >> 6;
                int kg    = rem & 63;
                const unsigned short* src = (plane & 1) ? curlo : curhi;
                gp[r2] = &src[(size_t)(bbase + row) * H + (plane >> 1) * 512 + kg * 8];
                ld[r2] = plane * PLANE + row * LROW + kg * 8;
            }
            uint4 v0, v1, v2, v3, v4;
            asm volatile(
                "global_load_dwordx4 %0, %5, off sc0 sc1\n\t"
                "global_load_dwordx4 %1, %6, off sc0 sc1\n\t"
                "global_load_dwordx4 %2, %7, off sc0 sc1\n\t"
                "global_load_dwordx4 %3, %8, off sc0 sc1\n\t"
                "global_load_dwordx4 %4, %9, off sc0 sc1\n\t"
                "s_waitcnt vmcnt(0)"
                : "=&v"(v0), "=&v"(v1), "=&v"(v2), "=&v"(v3), "=&v"(v4)
                : "v"(gp[0]), "v"(gp[1]), "v"(gp[2]), "v"(gp[3]), "v"(gp[4])
                : "memory");
            *(uint4*)&sA[ld[0]] = v0;
            *(uint4*)&sA[ld[1]] = v1;
            *(uint4*)&sA[ld[2]] = v2;
            *(uint4*)&sA[ld[3]] = v3;
            *(uint4*)&sA[ld[4]] = v4;
            if (tid < 256) {                      // tail: granules 3840..4095 (plane 3)
                int gi = 5 * NTHR + tid;
                int rem = gi & 1023;
                int row = rem >> 6;
                int kg  = rem & 63;
                const unsigned short* p = &curlo[(size_t)(bbase + row) * H + 512 + kg * 8];
                uint4 v5;
                asm volatile(
                    "global_load_dwordx4 %0, %1, off sc0 sc1\n\t"
                    "s_waitcnt vmcnt(0)"
                    : "=&v"(v5) : "v"(p) : "memory");
                *(uint4*)&sA[3 * PLANE + row * LROW + kg * 8] = v5;
            }
            __syncthreads();

            // ---- fused 32-kcg loop: depth-4 weight pipeline, depth-2 A pipeline ----
            uint4 wph[4], wpl[4];
#pragma unroll
            for (int p = 0; p < 4; ++p) {
                wph[p] = bh[(size_t)p * 64];
                wpl[p] = bl[(size_t)p * 64];
            }
            short8 pa_h[2], pa_l[2];
            pa_h[0] = *(const short8*)&sA[aoffm + q * 8];
            pa_l[0] = *(const short8*)&sA[PLANE + aoffm + q * 8];
#pragma unroll
            for (int kcg = 0; kcg < 32; ++kcg) {
                const int s = kcg & 3;
                if (kcg + 1 < 32) {
                    const int kn   = kcg + 1;
                    const int base = (kn >> 4) * 2 * PLANE;
                    const int koff = (kn & 15) * 32 + q * 8;
                    pa_h[kn & 1] = *(const short8*)&sA[base + aoffm + koff];
                    pa_l[kn & 1] = *(const short8*)&sA[base + PLANE + aoffm + koff];
                }
                short8 Bh = __builtin_bit_cast(short8, wph[s]);
                short8 Bl = __builtin_bit_cast(short8, wpl[s]);
                if (kcg + 4 < 32) {
                    wph[s] = bh[(size_t)(kcg + 4) * 64];
                    wpl[s] = bl[(size_t)(kcg + 4) * 64];
                }
                const short8 a_h = pa_h[kcg & 1];
                const short8 a_l = pa_l[kcg & 1];
                acc = __builtin_amdgcn_mfma_f32_16x16x32_bf16(a_h, Bh, acc, 0, 0, 0);
                acc = __builtin_amdgcn_mfma_f32_16x16x32_bf16(a_h, Bl, acc, 0, 0, 0);
                acc = __builtin_amdgcn_mfma_f32_16x16x32_bf16(a_l, Bh, acc, 0, 0, 0);
            }
        }

        __syncthreads();
        float* sG = (float*)sA;  // 6 gate planes [16 x 32] fp32 (12 KB, aliases sA)
        {
            // C/D layout: col = lane&15, row = (lane>>4)*4 + reg  [m89/m91 verified]
#pragma unroll
            for (int r = 0; r < 4; ++r) {
                int mrow = q * 4 + r;
                sG[g * 512 + mrow * 32 + m0 + half * 16] = acc[r];
            }
        }
        __syncthreads();

        // epilogue: 256 threads x 2 adjacent elements (packed u32 h' stores)
        if (tid < 256) {
            const int e0   = tid * 2;
            const int mloc = e0 >> 5;
            const int b    = bbase + mloc;
            const int i0   = ibase0 + (e0 & 31);
            const size_t hidx0 = (size_t)b * H + i0;
            float hn[2];
            unsigned short nh[2], nl[2];
#pragma unroll
            for (int j = 0; j < 2; ++j) {
                const int e = e0 + j;
                const int nloc = e & 31;
                float xz = sG[e], xr = sG[512 + e], xh = sG[1024 + e];
                float hz = sG[1536 + e], hr = sG[2048 + e], hh = sG[2560 + e];
                float zlin = xz + sBias[nloc]      + hz + sBias[96 + nloc];
                float rlin = xr + sBias[32 + nloc] + hr + sBias[128 + nloc];
                float xht  = xh + sBias[64 + nloc];
                float hht  = hh + sBias[160 + nloc];   // recurrent bias INSIDE r*(...)
                float z  = 1.0f / (1.0f + expf(-zlin));
                float r  = 1.0f / (1.0f + expf(-rlin));
                float hc = tanhf(xht + r * hht);
                float hold = t ? sHold[e]
                               : (bits2f(curhi[hidx0 + j]) + bits2f(curlo[hidx0 + j]));
                float hnew = z * hold + (1.0f - z) * hc;
                sHold[e] = hnew;
                hn[j] = hnew;
                split_bf(hnew, nh[j], nl[j]);
            }
            if (t < TSTEPS - 1) {
                unsigned int hiw = (unsigned int)nh[0] | ((unsigned int)nh[1] << 16);
                unsigned int low = (unsigned int)nl[0] | ((unsigned int)nl[1] << 16);
                __hip_atomic_store((unsigned int*)&dsthi[hidx0], hiw,
                                   __ATOMIC_RELAXED, __HIP_MEMORY_SCOPE_AGENT);
                __hip_atomic_store((unsigned int*)&dstlo[hidx0], low,
                                   __ATOMIC_RELAXED, __HIP_MEMORY_SCOPE_AGENT);
            }
            const size_t o1 = (size_t)b * (TSTEPS * H) + (size_t)t * H + i0;
            if (isbf) {
                outb[o1]     = __float2bfloat16(hn[0]);
                outb[o1 + 1] = __float2bfloat16(hn[1]);
                if (t == TSTEPS - 1) {
                    outb[(size_t)BATCH * TSTEPS * H + hidx0]     = __float2bfloat16(hn[0]);
                    outb[(size_t)BATCH * TSTEPS * H + hidx0 + 1] = __float2bfloat16(hn[1]);
                }
            } else {
                outf[o1]     = hn[0];
                outf[o1 + 1] = hn[1];
                if (t == TSTEPS - 1) {
                    outf[(size_t)BATCH * TSTEPS * H + hidx0]     = hn[0];
                    outf[(size_t)BATCH * TSTEPS * H + hidx0 + 1] = hn[1];
                }
            }
        }

        // ---- GLOBAL lockstep barrier (RMW counter — R4-proven) ----
        if (t < TSTEPS - 1) {
            asm volatile("s_waitcnt vmcnt(0)" ::: "memory");  // own h' stores acked
            __syncthreads();
            if (tid == 0) {
                __hip_atomic_fetch_add(bar, 1u, __ATOMIC_RELAXED, __HIP_MEMORY_SCOPE_AGENT);
                const unsigned int target = (unsigned int)NBLK * (unsigned int)(t + 1);
                while (__hip_atomic_load(bar, __ATOMIC_RELAXED, __HIP_MEMORY_SCOPE_AGENT) < target) {
                    __builtin_amdgcn_s_sleep(2);
                }
            }
            __syncthreads();
        }
    }
}

extern "C" void kernel_launch(void* const* d_in, const int* in_sizes, int n_in,
                              void* d_out, int out_size, void* d_ws, size_t ws_size,
                              hipStream_t stream) {
    const void* cin  = d_in[0];
    const void* hs   = d_in[1];
    const void* Kw   = d_in[2];
    const void* Rw   = d_in[3];
    const void* bias = d_in[4];

    char* ws = (char*)d_ws;
    int* flag = (int*)ws;
    unsigned int* bar = (unsigned int*)(ws + BAR_OFF);
    __hip_bfloat16* pwh = (__hip_bfloat16*)(ws + PW_OFF);
    __hip_bfloat16* pwl = (__hip_bfloat16*)(ws + PWL_OFF);
    unsigned short* xhi  = (unsigned short*)(ws + XHI_OFF);
    unsigned short* xlo  = (unsigned short*)(ws + XLO_OFF);
    unsigned short* h0hi = (unsigned short*)(ws + H0HI_OFF);
    unsigned short* h0lo = (unsigned short*)(ws + H0LO_OFF);
    unsigned short* h1hi = (unsigned short*)(ws + H1HI_OFF);
    unsigned short* h1lo = (unsigned short*)(ws + H1LO_OFF);

    detect_dtype<<<1, 256, 0, stream>>>((const unsigned int*)Kw, flag);
    pack_w<<<3072, 256, 0, stream>>>(Kw, Rw, pwh, pwl, flag);
    init_bufs<<<512, 256, 0, stream>>>(cin, hs, xhi, xlo, h0hi, h0lo, bar, flag);

    const unsigned short* xhi_c = xhi;
    const unsigned short* xlo_c = xlo;
    const __hip_bfloat16* pwh_c = pwh;
    const __hip_bfloat16* pwl_c = pwl;
    const int* flag_c = flag;
    void* kargs[] = {
        (void*)&xhi_c, (void*)&xlo_c,
        (void*)&h0hi, (void*)&h0lo, (void*)&h1hi, (void*)&h1lo,
        (void*)&pwh_c, (void*)&pwl_c,
        (void*)&bias, (void*)&d_out, (void*)&bar, (void*)&flag_c
    };
    hipLaunchCooperativeKernel((void*)gru_persistent, dim3(256), dim3(NTHR),
                               kargs, 0, stream);
}

// Round 7
// 4843.633 us; speedup vs baseline: 1.3351x; 1.1576x over previous
//
#include <hip/hip_runtime.h>
#include <hip/hip_bf16.h>

#define H 1024
#define B3H 3072
#define BATCH 128
#define TSTEPS 256
#define LROW 520                 // 512 k-chunk + 8 pad (shorts)
#define PLANE (16 * LROW)        // one 16-row bf16 plane per chunk
#define NBLK 256
#define NTHR 768                 // 12 waves: (gate, n-half)

typedef __attribute__((ext_vector_type(8))) short short8;
typedef __attribute__((ext_vector_type(4))) float f32x4;

static __device__ __forceinline__ float bf2f(__hip_bfloat16 v) { return __bfloat162float(v); }
static __device__ __forceinline__ unsigned short f2bf_bits(float f) {
    __hip_bfloat16 h = __float2bfloat16(f);
    return __builtin_bit_cast(unsigned short, h);
}
static __device__ __forceinline__ float bits2f(unsigned short b) {
    return bf2f(__builtin_bit_cast(__hip_bfloat16, b));
}
static __device__ __forceinline__ unsigned short bfbits(__hip_bfloat16 v) {
    return __builtin_bit_cast(unsigned short, v);
}
static __device__ __forceinline__ void split_bf(float v, unsigned short& hi, unsigned short& lo) {
    hi = f2bf_bits(v);
    lo = f2bf_bits(v - bits2f(hi));
}

// ws layout
#define BAR_OFF  128                       // 8 group counters, 128 B apart
#define PW_OFF   2048
#define PWL_OFF  (PW_OFF + 12582912)
#define XHI_OFF  (PWL_OFF + 12582912)
#define XLO_OFF  (XHI_OFF + 262144)
#define H0HI_OFF (XLO_OFF + 262144)
#define H0LO_OFF (H0HI_OFF + 262144)
#define H1HI_OFF (H0LO_OFF + 262144)
#define H1LO_OFF (H1HI_OFF + 262144)

__global__ void detect_dtype(const unsigned int* __restrict__ w, int* __restrict__ flag) {
    __shared__ int cnt[256];
    int c = 0;
    for (int i = threadIdx.x; i < 4096; i += 256) {
        unsigned int v = (w[i] >> 8) & 0x7f;
        c += (v >= 0x33 && v <= 0x3f) ? 1 : 0;
    }
    cnt[threadIdx.x] = c;
    __syncthreads();
    for (int s = 128; s > 0; s >>= 1) {
        if (threadIdx.x < s) cnt[threadIdx.x] += cnt[threadIdx.x + s];
        __syncthreads();
    }
    if (threadIdx.x == 0) *flag = (cnt[0] * 2 > 4096) ? 1 : 0;
}

// Pack W into MFMA B-fragment layout, bf16 hi/lo pair (unchanged — verified).
__global__ void pack_w(const void* __restrict__ Kp, const void* __restrict__ Rp,
                       __hip_bfloat16* __restrict__ pwh, __hip_bfloat16* __restrict__ pwl,
                       const int* __restrict__ flag) {
    int idx = blockIdx.x * 256 + threadIdx.x;
    int lane = idx & 63;
    int kc   = (idx >> 6) & 31;
    int ns   = (idx >> 11) & 1;
    int it   = (idx >> 12) & 31;
    int g    = idx >> 17;
    if (g >= 6) return;
    const int isbf = *flag;
    int col   = (g % 3) * 1024 + it * 32 + ns * 16 + (lane & 15);
    int kbase = kc * 32 + (lane >> 4) * 8;
    unsigned short eh[8], el[8];
    if (isbf) {
        const __hip_bfloat16* src = (const __hip_bfloat16*)((g < 3) ? Kp : Rp);
#pragma unroll
        for (int j = 0; j < 8; ++j) { eh[j] = bfbits(src[(size_t)(kbase + j) * B3H + col]); el[j] = 0; }
    } else {
        const float* src = (const float*)((g < 3) ? Kp : Rp);
#pragma unroll
        for (int j = 0; j < 8; ++j) split_bf(src[(size_t)(kbase + j) * B3H + col], eh[j], el[j]);
    }
    uint4 vh, vl;
    vh.x = (unsigned int)eh[0] | ((unsigned int)eh[1] << 16);
    vh.y = (unsigned int)eh[2] | ((unsigned int)eh[3] << 16);
    vh.z = (unsigned int)eh[4] | ((unsigned int)eh[5] << 16);
    vh.w = (unsigned int)eh[6] | ((unsigned int)eh[7] << 16);
    vl.x = (unsigned int)el[0] | ((unsigned int)el[1] << 16);
    vl.y = (unsigned int)el[2] | ((unsigned int)el[3] << 16);
    vl.z = (unsigned int)el[4] | ((unsigned int)el[5] << 16);
    vl.w = (unsigned int)el[6] | ((unsigned int)el[7] << 16);
    *(uint4*)(pwh + (size_t)idx * 8) = vh;
    *(uint4*)(pwl + (size_t)idx * 8) = vl;
}

// Inputs -> pre-split bf16 hi/lo planes. Also zeroes the barrier counters.
__global__ void init_bufs(const void* __restrict__ cin, const void* __restrict__ hs,
                          unsigned short* __restrict__ xhi, unsigned short* __restrict__ xlo,
                          unsigned short* __restrict__ hhi, unsigned short* __restrict__ hlo,
                          unsigned int* __restrict__ bar,
                          const int* __restrict__ flag) {
    int i = blockIdx.x * 256 + threadIdx.x;
    if (blockIdx.x == 0 && threadIdx.x < 480) bar[threadIdx.x] = 0;
    if (i >= BATCH * H) return;
    float xv, hv;
    if (*flag) {
        xv = bf2f(((const __hip_bfloat16*)cin)[i]);
        hv = bf2f(((const __hip_bfloat16*)hs)[i]);
    } else {
        xv = ((const float*)cin)[i];
        hv = ((const float*)hs)[i];
    }
    unsigned short a, b;
    split_bf(xv, a, b); xhi[i] = a; xlo[i] = b;
    split_bf(hv, a, b); hhi[i] = a; hlo[i] = b;
}

// ---------------------------------------------------------------------------
// Persistent GRU. R7 = R6 (best: 5607 µs) with:
//  (1) per-bt-GROUP barrier: block (bt,it) consumes h rows produced only by
//      its own 32-block bt-group -> sync domain shrinks 256->32 (8x less RMW
//      serialization on the counter line; straggler max-of-32 not max-of-256).
//      R3's group-barrier regression is attributed to batched-ATOMIC staging
//      (R5 showed identical 34MB/step FETCH with a FULL barrier); sc1 traffic
//      doesn't allocate in L2, so group drift can't evict weights.
//  (2) uniform staging: all 768 threads issue 6 wrapped loads under ONE
//      vmcnt(0) (R6 gave 256 threads a second serialized round trip).
// ---------------------------------------------------------------------------
__launch_bounds__(NTHR, 1)
__global__ void gru_persistent(const unsigned short* __restrict__ xhi,
                               const unsigned short* __restrict__ xlo,
                               unsigned short* __restrict__ h0hi,
                               unsigned short* __restrict__ h0lo,
                               unsigned short* __restrict__ h1hi,
                               unsigned short* __restrict__ h1lo,
                               const __hip_bfloat16* __restrict__ pwh,
                               const __hip_bfloat16* __restrict__ pwl,
                               const void* __restrict__ bias,
                               void* __restrict__ out,
                               unsigned int* __restrict__ bar,
                               const int* __restrict__ flag) {
    // t=0 planes: [Ahi][Alo][Bhi][Blo] of chunk c; t>=1: [c0hi][c0lo][c1hi][c1lo]
    __shared__ unsigned short sA[4 * PLANE];  // 66560 B (aliased as sG fp32 post-GEMM)
    __shared__ float sHold[512];              // this block's h tile, full f32
    __shared__ float sBias[192];              // 6 gates x 32 cols

    const int tid  = threadIdx.x;
    const int w    = tid >> 6;        // wave 0..11
    const int g    = w >> 1;          // gate 0..5
    const int half = w & 1;           // n-half 0..1
    const int lane = tid & 63;
    const int bt = blockIdx.x >> 5;   // 0..7, 16-row tiles (= sync group)
    const int it = blockIdx.x & 31;   // 0..31, 32-col slices
    const int bbase = bt * 16;
    const int m0 = lane & 15;
    const int q  = lane >> 4;
    const int aoffm = m0 * LROW;
    const int ibase0 = it * 32;
    const int isbf = *flag;

    // preload bias once
    {
        const __hip_bfloat16* bias_b = (const __hip_bfloat16*)bias;
        const float* bias_f = (const float*)bias;
        for (int e = tid; e < 192; e += NTHR) {
            int gg = e >> 5;
            int i  = ibase0 + (e & 31);
            int src = (gg < 3) ? (gg * 1024 + i) : (B3H + (gg - 3) * 1024 + i);
            sBias[e] = isbf ? bf2f(bias_b[src]) : bias_f[src];
        }
    }

    // this wave's single weight stream pair (16 cols)
    const size_t boff = ((size_t)((g * 32 + it) * 2 + half) * 32) * 64 + lane;
    const uint4* bh = (const uint4*)pwh + boff;
    const uint4* bl = (const uint4*)pwl + boff;

    __hip_bfloat16* outb = (__hip_bfloat16*)out;
    float* outf = (float*)out;

    for (int t = 0; t < TSTEPS; ++t) {
        const int cur = t & 1;
        const unsigned short* curhi = cur ? h1hi : h0hi;
        const unsigned short* curlo = cur ? h1lo : h0lo;
        unsigned short* dsthi = cur ? h0hi : h1hi;
        unsigned short* dstlo = cur ? h0lo : h1lo;

        f32x4 acc = {0.f, 0.f, 0.f, 0.f};

        if (t == 0) {
            // ---- t=0 (once): x (gates 0-2) + h0 (gates 3-5), cached loads ----
            const unsigned short* aH0 = sA + ((g < 3) ? 0 : 2) * PLANE;
            const unsigned short* aL0 = aH0 + PLANE;
            for (int c = 0; c < 2; ++c) {
                if (c) __syncthreads();
                const int kstart = c * 512;
                for (int g4 = tid; g4 < 4096; g4 += NTHR) {
                    int plane = g4 >> 10;
                    int rem   = g4 & 1023;
                    int row   = rem >> 6;
                    int kg    = rem & 63;
                    const unsigned short* src =
                        (plane == 0) ? xhi : (plane == 1) ? xlo : (plane == 2) ? curhi : curlo;
                    uint4 v = *(const uint4*)&src[(size_t)(bbase + row) * H + kstart + kg * 8];
                    *(uint4*)&sA[plane * PLANE + row * LROW + kg * 8] = v;
                }
                __syncthreads();
#pragma unroll 4
                for (int kc = 0; kc < 16; ++kc) {
                    const int kcg = c * 16 + kc;
                    short8 Bh = __builtin_bit_cast(short8, bh[(size_t)kcg * 64]);
                    short8 Bl = __builtin_bit_cast(short8, bl[(size_t)kcg * 64]);
                    const int koff = kc * 32 + q * 8;
                    short8 a_h = *(const short8*)&aH0[aoffm + koff];
                    short8 a_l = *(const short8*)&aL0[aoffm + koff];
                    acc = __builtin_amdgcn_mfma_f32_16x16x32_bf16(a_h, Bh, acc, 0, 0, 0);
                    acc = __builtin_amdgcn_mfma_f32_16x16x32_bf16(a_h, Bl, acc, 0, 0, 0);
                    acc = __builtin_amdgcn_mfma_f32_16x16x32_bf16(a_l, Bh, acc, 0, 0, 0);
                }
            }
        } else {
            // ---- t>=1: batched device-coherent staging, non-atomic sc0 sc1 ----
            // 4096 x 16B granules (planes 0=c0hi 1=c0lo 2=c1hi 3=c1lo).
            // 6 loads/thread, gi wrapped mod 4096 (benign duplicate of same
            // data for 512 threads) -> ONE vmcnt(0) for the whole stage.
            const unsigned short* gp[6];
            int ld[6];
#pragma unroll
            for (int r2 = 0; r2 < 6; ++r2) {
                int gi = r2 * NTHR + tid;
                if (gi >= 4096) gi -= 4096;
                int plane = gi >> 10;
                int rem   = gi & 1023;
                int row   = rem >> 6;
                int kg    = rem & 63;
                const unsigned short* src = (plane & 1) ? curlo : curhi;
                gp[r2] = &src[(size_t)(bbase + row) * H + (plane >> 1) * 512 + kg * 8];
                ld[r2] = plane * PLANE + row * LROW + kg * 8;
            }
            uint4 v0, v1, v2, v3, v4, v5;
            asm volatile(
                "global_load_dwordx4 %0, %6, off sc0 sc1\n\t"
                "global_load_dwordx4 %1, %7, off sc0 sc1\n\t"
                "global_load_dwordx4 %2, %8, off sc0 sc1\n\t"
                "global_load_dwordx4 %3, %9, off sc0 sc1\n\t"
                "global_load_dwordx4 %4, %10, off sc0 sc1\n\t"
                "global_load_dwordx4 %5, %11, off sc0 sc1\n\t"
                "s_waitcnt vmcnt(0)"
                : "=&v"(v0), "=&v"(v1), "=&v"(v2), "=&v"(v3), "=&v"(v4), "=&v"(v5)
                : "v"(gp[0]), "v"(gp[1]), "v"(gp[2]), "v"(gp[3]), "v"(gp[4]), "v"(gp[5])
                : "memory");
            *(uint4*)&sA[ld[0]] = v0;
            *(uint4*)&sA[ld[1]] = v1;
            *(uint4*)&sA[ld[2]] = v2;
            *(uint4*)&sA[ld[3]] = v3;
            *(uint4*)&sA[ld[4]] = v4;
            *(uint4*)&sA[ld[5]] = v5;
            __syncthreads();

            // ---- fused 32-kcg loop: depth-4 weight pipeline, depth-2 A pipeline ----
            uint4 wph[4], wpl[4];
#pragma unroll
            for (int p = 0; p < 4; ++p) {
                wph[p] = bh[(size_t)p * 64];
                wpl[p] = bl[(size_t)p * 64];
            }
            short8 pa_h[2], pa_l[2];
            pa_h[0] = *(const short8*)&sA[aoffm + q * 8];
            pa_l[0] = *(const short8*)&sA[PLANE + aoffm + q * 8];
#pragma unroll
            for (int kcg = 0; kcg < 32; ++kcg) {
                const int s = kcg & 3;
                if (kcg + 1 < 32) {
                    const int kn   = kcg + 1;
                    const int base = (kn >> 4) * 2 * PLANE;
                    const int koff = (kn & 15) * 32 + q * 8;
                    pa_h[kn & 1] = *(const short8*)&sA[base + aoffm + koff];
                    pa_l[kn & 1] = *(const short8*)&sA[base + PLANE + aoffm + koff];
                }
                short8 Bh = __builtin_bit_cast(short8, wph[s]);
                short8 Bl = __builtin_bit_cast(short8, wpl[s]);
                if (kcg + 4 < 32) {
                    wph[s] = bh[(size_t)(kcg + 4) * 64];
                    wpl[s] = bl[(size_t)(kcg + 4) * 64];
                }
                const short8 a_h = pa_h[kcg & 1];
                const short8 a_l = pa_l[kcg & 1];
                acc = __builtin_amdgcn_mfma_f32_16x16x32_bf16(a_h, Bh, acc, 0, 0, 0);
                acc = __builtin_amdgcn_mfma_f32_16x16x32_bf16(a_h, Bl, acc, 0, 0, 0);
                acc = __builtin_amdgcn_mfma_f32_16x16x32_bf16(a_l, Bh, acc, 0, 0, 0);
            }
        }

        __syncthreads();
        float* sG = (float*)sA;  // 6 gate planes [16 x 32] fp32 (12 KB, aliases sA)
        {
            // C/D layout: col = lane&15, row = (lane>>4)*4 + reg  [m89/m91 verified]
#pragma unroll
            for (int r = 0; r < 4; ++r) {
                int mrow = q * 4 + r;
                sG[g * 512 + mrow * 32 + m0 + half * 16] = acc[r];
            }
        }
        __syncthreads();

        // epilogue: 256 threads x 2 adjacent elements (packed u32 h' stores)
        if (tid < 256) {
            const int e0   = tid * 2;
            const int mloc = e0 >> 5;
            const int b    = bbase + mloc;
            const int i0   = ibase0 + (e0 & 31);
            const size_t hidx0 = (size_t)b * H + i0;
            float hn[2];
            unsigned short nh[2], nl[2];
#pragma unroll
            for (int j = 0; j < 2; ++j) {
                const int e = e0 + j;
                const int nloc = e & 31;
                float xz = sG[e], xr = sG[512 + e], xh = sG[1024 + e];
                float hz = sG[1536 + e], hr = sG[2048 + e], hh = sG[2560 + e];
                float zlin = xz + sBias[nloc]      + hz + sBias[96 + nloc];
                float rlin = xr + sBias[32 + nloc] + hr + sBias[128 + nloc];
                float xht  = xh + sBias[64 + nloc];
                float hht  = hh + sBias[160 + nloc];   // recurrent bias INSIDE r*(...)
                float z  = 1.0f / (1.0f + expf(-zlin));
                float r  = 1.0f / (1.0f + expf(-rlin));
                float hc = tanhf(xht + r * hht);
                float hold = t ? sHold[e]
                               : (bits2f(curhi[hidx0 + j]) + bits2f(curlo[hidx0 + j]));
                float hnew = z * hold + (1.0f - z) * hc;
                sHold[e] = hnew;
                hn[j] = hnew;
                split_bf(hnew, nh[j], nl[j]);
            }
            if (t < TSTEPS - 1) {
                unsigned int hiw = (unsigned int)nh[0] | ((unsigned int)nh[1] << 16);
                unsigned int low = (unsigned int)nl[0] | ((unsigned int)nl[1] << 16);
                __hip_atomic_store((unsigned int*)&dsthi[hidx0], hiw,
                                   __ATOMIC_RELAXED, __HIP_MEMORY_SCOPE_AGENT);
                __hip_atomic_store((unsigned int*)&dstlo[hidx0], low,
                                   __ATOMIC_RELAXED, __HIP_MEMORY_SCOPE_AGENT);
            }
            const size_t o1 = (size_t)b * (TSTEPS * H) + (size_t)t * H + i0;
            if (isbf) {
                outb[o1]     = __float2bfloat16(hn[0]);
                outb[o1 + 1] = __float2bfloat16(hn[1]);
                if (t == TSTEPS - 1) {
                    outb[(size_t)BATCH * TSTEPS * H + hidx0]     = __float2bfloat16(hn[0]);
                    outb[(size_t)BATCH * TSTEPS * H + hidx0 + 1] = __float2bfloat16(hn[1]);
                }
            } else {
                outf[o1]     = hn[0];
                outf[o1 + 1] = hn[1];
                if (t == TSTEPS - 1) {
                    outf[(size_t)BATCH * TSTEPS * H + hidx0]     = hn[0];
                    outf[(size_t)BATCH * TSTEPS * H + hidx0 + 1] = hn[1];
                }
            }
        }

        // ---- per-bt-group barrier (32 blocks; groups are independent chains) ----
        if (t < TSTEPS - 1) {
            asm volatile("s_waitcnt vmcnt(0)" ::: "memory");  // own h' stores acked
            __syncthreads();
            if (tid == 0) {
                unsigned int* ctr = bar + (bt << 5);          // 128 B apart
                __hip_atomic_fetch_add(ctr, 1u, __ATOMIC_RELAXED, __HIP_MEMORY_SCOPE_AGENT);
                const unsigned int target = 32u * (unsigned int)(t + 1);
                while (__hip_atomic_load(ctr, __ATOMIC_RELAXED, __HIP_MEMORY_SCOPE_AGENT) < target) {
                    __builtin_amdgcn_s_sleep(1);
                }
            }
            __syncthreads();
        }
    }
}

extern "C" void kernel_launch(void* const* d_in, const int* in_sizes, int n_in,
                              void* d_out, int out_size, void* d_ws, size_t ws_size,
                              hipStream_t stream) {
    const void* cin  = d_in[0];
    const void* hs   = d_in[1];
    const void* Kw   = d_in[2];
    const void* Rw   = d_in[3];
    const void* bias = d_in[4];

    char* ws = (char*)d_ws;
    int* flag = (int*)ws;
    unsigned int* bar = (unsigned int*)(ws + BAR_OFF);
    __hip_bfloat16* pwh = (__hip_bfloat16*)(ws + PW_OFF);
    __hip_bfloat16* pwl = (__hip_bfloat16*)(ws + PWL_OFF);
    unsigned short* xhi  = (unsigned short*)(ws + XHI_OFF);
    unsigned short* xlo  = (unsigned short*)(ws + XLO_OFF);
    unsigned short* h0hi = (unsigned short*)(ws + H0HI_OFF);
    unsigned short* h0lo = (unsigned short*)(ws + H0LO_OFF);
    unsigned short* h1hi = (unsigned short*)(ws + H1HI_OFF);
    unsigned short* h1lo = (unsigned short*)(ws + H1LO_OFF);

    detect_dtype<<<1, 256, 0, stream>>>((const unsigned int*)Kw, flag);
    pack_w<<<3072, 256, 0, stream>>>(Kw, Rw, pwh, pwl, flag);
    init_bufs<<<512, 256, 0, stream>>>(cin, hs, xhi, xlo, h0hi, h0lo, bar, flag);

    const unsigned short* xhi_c = xhi;
    const unsigned short* xlo_c = xlo;
    const __hip_bfloat16* pwh_c = pwh;
    const __hip_bfloat16* pwl_c = pwl;
    const int* flag_c = flag;
    void* kargs[] = {
        (void*)&xhi_c, (void*)&xlo_c,
        (void*)&h0hi, (void*)&h0lo, (void*)&h1hi, (void*)&h1lo,
        (void*)&pwh_c, (void*)&pwl_c,
        (void*)&bias, (void*)&d_out, (void*)&bar, (void*)&flag_c
    };
    hipLaunchCooperativeKernel((void*)gru_persistent, dim3(256), dim3(NTHR),
                               kargs, 0, stream);
}

// Round 8
// 3911.385 us; speedup vs baseline: 1.6534x; 1.2383x over previous
//
#include <hip/hip_runtime.h>
#include <hip/hip_bf16.h>

#define H 1024
#define B3H 3072
#define BATCH 128
#define TSTEPS 256
#define LROW 520                 // 512 k-chunk + 8 pad (shorts)
#define PLANE32 (32 * LROW)      // one 32-row bf16 plane per chunk
#define NBLK 256
#define NTHR 768                 // 12 waves: (gate, k-half)

typedef __attribute__((ext_vector_type(8))) short short8;
typedef __attribute__((ext_vector_type(4))) float f32x4;

static __device__ __forceinline__ float bf2f(__hip_bfloat16 v) { return __bfloat162float(v); }
static __device__ __forceinline__ unsigned short f2bf_bits(float f) {
    __hip_bfloat16 h = __float2bfloat16(f);
    return __builtin_bit_cast(unsigned short, h);
}
static __device__ __forceinline__ float bits2f(unsigned short b) {
    return bf2f(__builtin_bit_cast(__hip_bfloat16, b));
}
static __device__ __forceinline__ unsigned short bfbits(__hip_bfloat16 v) {
    return __builtin_bit_cast(unsigned short, v);
}
static __device__ __forceinline__ void split_bf(float v, unsigned short& hi, unsigned short& lo) {
    hi = f2bf_bits(v);
    lo = f2bf_bits(v - bits2f(hi));
}

// ws layout
#define BAR_OFF  128                       // 256 arrival slots (u32)
#define PW_OFF   2048
#define PWL_OFF  (PW_OFF + 12582912)
#define XHI_OFF  (PWL_OFF + 12582912)
#define XLO_OFF  (XHI_OFF + 262144)
#define H0HI_OFF (XLO_OFF + 262144)
#define H0LO_OFF (H0HI_OFF + 262144)
#define H1HI_OFF (H0LO_OFF + 262144)
#define H1LO_OFF (H1HI_OFF + 262144)

__global__ void detect_dtype(const unsigned int* __restrict__ w, int* __restrict__ flag) {
    __shared__ int cnt[256];
    int c = 0;
    for (int i = threadIdx.x; i < 4096; i += 256) {
        unsigned int v = (w[i] >> 8) & 0x7f;
        c += (v >= 0x33 && v <= 0x3f) ? 1 : 0;
    }
    cnt[threadIdx.x] = c;
    __syncthreads();
    for (int s = 128; s > 0; s >>= 1) {
        if (threadIdx.x < s) cnt[threadIdx.x] += cnt[threadIdx.x + s];
        __syncthreads();
    }
    if (threadIdx.x == 0) *flag = (cnt[0] * 2 > 4096) ? 1 : 0;
}

// Pack W into MFMA B-fragment layout, bf16 hi/lo pair (unchanged — verified).
__global__ void pack_w(const void* __restrict__ Kp, const void* __restrict__ Rp,
                       __hip_bfloat16* __restrict__ pwh, __hip_bfloat16* __restrict__ pwl,
                       const int* __restrict__ flag) {
    int idx = blockIdx.x * 256 + threadIdx.x;
    int lane = idx & 63;
    int kc   = (idx >> 6) & 31;
    int ns   = (idx >> 11) & 1;
    int it   = (idx >> 12) & 31;
    int g    = idx >> 17;
    if (g >= 6) return;
    const int isbf = *flag;
    int col   = (g % 3) * 1024 + it * 32 + ns * 16 + (lane & 15);
    int kbase = kc * 32 + (lane >> 4) * 8;
    unsigned short eh[8], el[8];
    if (isbf) {
        const __hip_bfloat16* src = (const __hip_bfloat16*)((g < 3) ? Kp : Rp);
#pragma unroll
        for (int j = 0; j < 8; ++j) { eh[j] = bfbits(src[(size_t)(kbase + j) * B3H + col]); el[j] = 0; }
    } else {
        const float* src = (const float*)((g < 3) ? Kp : Rp);
#pragma unroll
        for (int j = 0; j < 8; ++j) split_bf(src[(size_t)(kbase + j) * B3H + col], eh[j], el[j]);
    }
    uint4 vh, vl;
    vh.x = (unsigned int)eh[0] | ((unsigned int)eh[1] << 16);
    vh.y = (unsigned int)eh[2] | ((unsigned int)eh[3] << 16);
    vh.z = (unsigned int)eh[4] | ((unsigned int)eh[5] << 16);
    vh.w = (unsigned int)eh[6] | ((unsigned int)eh[7] << 16);
    vl.x = (unsigned int)el[0] | ((unsigned int)el[1] << 16);
    vl.y = (unsigned int)el[2] | ((unsigned int)el[3] << 16);
    vl.z = (unsigned int)el[4] | ((unsigned int)el[5] << 16);
    vl.w = (unsigned int)el[6] | ((unsigned int)el[7] << 16);
    *(uint4*)(pwh + (size_t)idx * 8) = vh;
    *(uint4*)(pwl + (size_t)idx * 8) = vl;
}

// Inputs -> pre-split bf16 hi/lo planes. Also zeroes the arrival slots.
__global__ void init_bufs(const void* __restrict__ cin, const void* __restrict__ hs,
                          unsigned short* __restrict__ xhi, unsigned short* __restrict__ xlo,
                          unsigned short* __restrict__ hhi, unsigned short* __restrict__ hlo,
                          unsigned int* __restrict__ bar,
                          const int* __restrict__ flag) {
    int i = blockIdx.x * 256 + threadIdx.x;
    if (blockIdx.x == 0 && threadIdx.x < 480) bar[threadIdx.x] = 0;
    if (i >= BATCH * H) return;
    float xv, hv;
    if (*flag) {
        xv = bf2f(((const __hip_bfloat16*)cin)[i]);
        hv = bf2f(((const __hip_bfloat16*)hs)[i]);
    } else {
        xv = ((const float*)cin)[i];
        hv = ((const float*)hs)[i];
    }
    unsigned short a, b;
    split_bf(xv, a, b); xhi[i] = a; xlo[i] = b;
    split_bf(hv, a, b); hhi[i] = a; hlo[i] = b;
}

// ---------------------------------------------------------------------------
// Persistent GRU. R8: 32-row batch tiles (M=16 -> 32). Block = 32 rows x
// (6 gates x 16 cols); grid 256 = 4 bt x 64 it. 12 waves = (gate, k-half):
// each wave owns k in [kh*512, kh*512+512) for BOTH 16-row sub-tiles, so no
// weight fragment is fetched twice -> weights/block 768->384 KB (the ~5 µs
// per-CU L1-fill floor halves). Partial-k sums land in sG[gate][kh][mt], summed
// in the epilogue (f32). Barrier: arrival array (1 sc1 store/block; wave0
// polls its group's 64 slots, one per lane — no RMW serialization).
// ---------------------------------------------------------------------------
__launch_bounds__(NTHR, 1)
__global__ void gru_persistent(const unsigned short* __restrict__ xhi,
                               const unsigned short* __restrict__ xlo,
                               unsigned short* __restrict__ h0hi,
                               unsigned short* __restrict__ h0lo,
                               unsigned short* __restrict__ h1hi,
                               unsigned short* __restrict__ h1lo,
                               const __hip_bfloat16* __restrict__ pwh,
                               const __hip_bfloat16* __restrict__ pwl,
                               const void* __restrict__ bias,
                               void* __restrict__ out,
                               unsigned int* __restrict__ bar,
                               const int* __restrict__ flag) {
    // t=0 planes (per chunk): [xhi][xlo][hhi][hlo]; t>=1: [c0hi][c0lo][c1hi][c1lo]
    __shared__ unsigned short sA[4 * PLANE32];  // 133120 B (aliased by sG post-GEMM)
    __shared__ float sHold[512];                // 32 rows x 16 cols, full f32
    __shared__ float sBias[96];                 // 6 gates x 16 cols

    const int tid  = threadIdx.x;
    const int w    = tid >> 6;        // wave 0..11
    const int g    = w >> 1;          // gate 0..5
    const int kh   = w & 1;           // k-half 0..1
    const int lane = tid & 63;
    const int bt = blockIdx.x >> 6;   // 0..3, 32-row tiles (= sync group)
    const int it = blockIdx.x & 63;   // 0..63, 16-col slices (XCD = it%8)
    const int bbase = bt * 32;
    const int m0 = lane & 15;
    const int q  = lane >> 4;
    const int ibase0 = it * 16;
    const int isbf = *flag;

    // preload bias once
    {
        const __hip_bfloat16* bias_b = (const __hip_bfloat16*)bias;
        const float* bias_f = (const float*)bias;
        if (tid < 96) {
            int gg = tid >> 4;
            int i  = ibase0 + (tid & 15);
            int src = (gg < 3) ? (gg * 1024 + i) : (B3H + (gg - 3) * 1024 + i);
            sBias[tid] = isbf ? bf2f(bias_b[src]) : bias_f[src];
        }
    }

    // this wave's weight stream pair (16 cols; kcg entries kh*16..kh*16+15)
    const size_t boff = ((size_t)((g * 32 + (it >> 1)) * 2 + (it & 1)) * 32) * 64 + lane;
    const uint4* bh = (const uint4*)pwh + boff;
    const uint4* bl = (const uint4*)pwl + boff;

    __hip_bfloat16* outb = (__hip_bfloat16*)out;
    float* outf = (float*)out;

    for (int t = 0; t < TSTEPS; ++t) {
        const int cur = t & 1;
        const unsigned short* curhi = cur ? h1hi : h0hi;
        const unsigned short* curlo = cur ? h1lo : h0lo;
        unsigned short* dsthi = cur ? h0hi : h1hi;
        unsigned short* dstlo = cur ? h0lo : h1lo;

        f32x4 acc0 = {0.f, 0.f, 0.f, 0.f};   // rows  0..15 of this block
        f32x4 acc1 = {0.f, 0.f, 0.f, 0.f};   // rows 16..31

        if (t == 0) {
            // ---- t=0 (once): x (gates 0-2) + h0 (gates 3-5), cached loads ----
            for (int c = 0; c < 2; ++c) {
                if (c) __syncthreads();
                const int kstart = c * 512;
                for (int gi = tid; gi < 8192; gi += NTHR) {
                    int plane = gi >> 11;     // 0=xhi 1=xlo 2=hhi 3=hlo
                    int rem   = gi & 2047;
                    int row   = rem >> 6;     // 0..31
                    int kg    = rem & 63;
                    const unsigned short* src =
                        (plane == 0) ? xhi : (plane == 1) ? xlo : (plane == 2) ? curhi : curlo;
                    uint4 v = *(const uint4*)&src[(size_t)(bbase + row) * H + kstart + kg * 8];
                    *(uint4*)&sA[plane * PLANE32 + row * LROW + kg * 8] = v;
                }
                __syncthreads();
                if (kh == c) {
                    const unsigned short* aH0 = sA + ((g < 3) ? 0 : 2) * PLANE32;
                    const unsigned short* aL0 = aH0 + PLANE32;
#pragma unroll 4
                    for (int kc = 0; kc < 16; ++kc) {
                        const int kcg = c * 16 + kc;
                        short8 Bh = __builtin_bit_cast(short8, bh[(size_t)kcg * 64]);
                        short8 Bl = __builtin_bit_cast(short8, bl[(size_t)kcg * 64]);
                        const int koff = kc * 32 + q * 8;
                        short8 ah0 = *(const short8*)&aH0[m0 * LROW + koff];
                        short8 al0 = *(const short8*)&aL0[m0 * LROW + koff];
                        short8 ah1 = *(const short8*)&aH0[(16 + m0) * LROW + koff];
                        short8 al1 = *(const short8*)&aL0[(16 + m0) * LROW + koff];
                        acc0 = __builtin_amdgcn_mfma_f32_16x16x32_bf16(ah0, Bh, acc0, 0, 0, 0);
                        acc0 = __builtin_amdgcn_mfma_f32_16x16x32_bf16(ah0, Bl, acc0, 0, 0, 0);
                        acc0 = __builtin_amdgcn_mfma_f32_16x16x32_bf16(al0, Bh, acc0, 0, 0, 0);
                        acc1 = __builtin_amdgcn_mfma_f32_16x16x32_bf16(ah1, Bh, acc1, 0, 0, 0);
                        acc1 = __builtin_amdgcn_mfma_f32_16x16x32_bf16(ah1, Bl, acc1, 0, 0, 0);
                        acc1 = __builtin_amdgcn_mfma_f32_16x16x32_bf16(al1, Bh, acc1, 0, 0, 0);
                    }
                }
            }
        } else {
            // ---- t>=1: batched device-coherent staging (non-atomic sc0 sc1) ----
            // 8192 x 16B granules (planes 0=c0hi 1=c0lo 2=c1hi 3=c1lo, 32 rows).
            // 11 wrapped loads/thread under ONE vmcnt(0).
            const unsigned short* gp[11];
            int ld[11];
#pragma unroll
            for (int r2 = 0; r2 < 11; ++r2) {
                int gi = r2 * NTHR + tid;
                if (gi >= 8192) gi -= 8192;
                int plane = gi >> 11;
                int rem   = gi & 2047;
                int row   = rem >> 6;
                int kg    = rem & 63;
                const unsigned short* src = (plane & 1) ? curlo : curhi;
                gp[r2] = &src[(size_t)(bbase + row) * H + (plane >> 1) * 512 + kg * 8];
                ld[r2] = plane * PLANE32 + row * LROW + kg * 8;
            }
            uint4 v0, v1, v2, v3, v4, v5, v6, v7, v8, v9, v10;
            asm volatile(
                "global_load_dwordx4 %0, %11, off sc0 sc1\n\t"
                "global_load_dwordx4 %1, %12, off sc0 sc1\n\t"
                "global_load_dwordx4 %2, %13, off sc0 sc1\n\t"
                "global_load_dwordx4 %3, %14, off sc0 sc1\n\t"
                "global_load_dwordx4 %4, %15, off sc0 sc1\n\t"
                "global_load_dwordx4 %5, %16, off sc0 sc1\n\t"
                "global_load_dwordx4 %6, %17, off sc0 sc1\n\t"
                "global_load_dwordx4 %7, %18, off sc0 sc1\n\t"
                "global_load_dwordx4 %8, %19, off sc0 sc1\n\t"
                "global_load_dwordx4 %9, %20, off sc0 sc1\n\t"
                "global_load_dwordx4 %10, %21, off sc0 sc1\n\t"
                "s_waitcnt vmcnt(0)"
                : "=&v"(v0), "=&v"(v1), "=&v"(v2), "=&v"(v3), "=&v"(v4), "=&v"(v5),
                  "=&v"(v6), "=&v"(v7), "=&v"(v8), "=&v"(v9), "=&v"(v10)
                : "v"(gp[0]), "v"(gp[1]), "v"(gp[2]), "v"(gp[3]), "v"(gp[4]), "v"(gp[5]),
                  "v"(gp[6]), "v"(gp[7]), "v"(gp[8]), "v"(gp[9]), "v"(gp[10])
                : "memory");
            *(uint4*)&sA[ld[0]]  = v0;
            *(uint4*)&sA[ld[1]]  = v1;
            *(uint4*)&sA[ld[2]]  = v2;
            *(uint4*)&sA[ld[3]]  = v3;
            *(uint4*)&sA[ld[4]]  = v4;
            *(uint4*)&sA[ld[5]]  = v5;
            *(uint4*)&sA[ld[6]]  = v6;
            *(uint4*)&sA[ld[7]]  = v7;
            *(uint4*)&sA[ld[8]]  = v8;
            *(uint4*)&sA[ld[9]]  = v9;
            *(uint4*)&sA[ld[10]] = v10;
            __syncthreads();

            // ---- 16-kcg loop (this wave's k-half): depth-4 weight pipeline ----
            uint4 wph[4], wpl[4];
#pragma unroll
            for (int p = 0; p < 4; ++p) {
                wph[p] = bh[(size_t)(kh * 16 + p) * 64];
                wpl[p] = bl[(size_t)(kh * 16 + p) * 64];
            }
            const int aBase = kh * 2 * PLANE32;
#pragma unroll
            for (int kc = 0; kc < 16; ++kc) {
                const int s = kc & 3;
                short8 Bh = __builtin_bit_cast(short8, wph[s]);
                short8 Bl = __builtin_bit_cast(short8, wpl[s]);
                if (kc + 4 < 16) {
                    wph[s] = bh[(size_t)(kh * 16 + kc + 4) * 64];
                    wpl[s] = bl[(size_t)(kh * 16 + kc + 4) * 64];
                }
                const int koff = kc * 32 + q * 8;
                short8 ah0 = *(const short8*)&sA[aBase + m0 * LROW + koff];
                short8 al0 = *(const short8*)&sA[aBase + PLANE32 + m0 * LROW + koff];
                short8 ah1 = *(const short8*)&sA[aBase + (16 + m0) * LROW + koff];
                short8 al1 = *(const short8*)&sA[aBase + PLANE32 + (16 + m0) * LROW + koff];
                acc0 = __builtin_amdgcn_mfma_f32_16x16x32_bf16(ah0, Bh, acc0, 0, 0, 0);
                acc0 = __builtin_amdgcn_mfma_f32_16x16x32_bf16(ah0, Bl, acc0, 0, 0, 0);
                acc0 = __builtin_amdgcn_mfma_f32_16x16x32_bf16(al0, Bh, acc0, 0, 0, 0);
                acc1 = __builtin_amdgcn_mfma_f32_16x16x32_bf16(ah1, Bh, acc1, 0, 0, 0);
                acc1 = __builtin_amdgcn_mfma_f32_16x16x32_bf16(ah1, Bl, acc1, 0, 0, 0);
                acc1 = __builtin_amdgcn_mfma_f32_16x16x32_bf16(al1, Bh, acc1, 0, 0, 0);
            }
        }

        __syncthreads();
        // sG: [gate][kh][mt] tiles of 16x16 f32 = 24 x 256 = 24 KB (aliases sA)
        float* sG = (float*)sA;
        {
            // C/D layout: col = lane&15, row = (lane>>4)*4 + reg  [m89/m91 verified]
#pragma unroll
            for (int r = 0; r < 4; ++r) {
                int mrow = q * 4 + r;
                sG[((g * 2 + kh) * 2 + 0) * 256 + mrow * 16 + m0] = acc0[r];
                sG[((g * 2 + kh) * 2 + 1) * 256 + mrow * 16 + m0] = acc1[r];
            }
        }
        __syncthreads();

        // epilogue: 256 threads x 2 adjacent cols (packed u32 h' stores)
        if (tid < 256) {
            const int e0   = tid * 2;
            const int mloc = e0 >> 4;          // 0..31
            const int nl0  = e0 & 15;          // even
            const int mt   = mloc >> 4;
            const int rt   = mloc & 15;
            const int b    = bbase + mloc;
            const int i0   = ibase0 + nl0;
            const size_t hidx0 = (size_t)b * H + i0;
            float hn[2];
            unsigned short nh[2], nl[2];
#pragma unroll
            for (int j = 0; j < 2; ++j) {
                const int nloc = nl0 + j;
                const int base = rt * 16 + nloc;
                float xz = sG[(0 * 4 + mt) * 256 + base] + sG[(0 * 4 + 2 + mt) * 256 + base];
                float xr = sG[(1 * 4 + mt) * 256 + base] + sG[(1 * 4 + 2 + mt) * 256 + base];
                float xh = sG[(2 * 4 + mt) * 256 + base] + sG[(2 * 4 + 2 + mt) * 256 + base];
                float hz = sG[(3 * 4 + mt) * 256 + base] + sG[(3 * 4 + 2 + mt) * 256 + base];
                float hr = sG[(4 * 4 + mt) * 256 + base] + sG[(4 * 4 + 2 + mt) * 256 + base];
                float hh = sG[(5 * 4 + mt) * 256 + base] + sG[(5 * 4 + 2 + mt) * 256 + base];
                float zlin = xz + sBias[nloc]      + hz + sBias[48 + nloc];
                float rlin = xr + sBias[16 + nloc] + hr + sBias[64 + nloc];
                float xht  = xh + sBias[32 + nloc];
                float hht  = hh + sBias[80 + nloc];   // recurrent bias INSIDE r*(...)
                float z  = 1.0f / (1.0f + expf(-zlin));
                float r  = 1.0f / (1.0f + expf(-rlin));
                float hc = tanhf(xht + r * hht);
                const int e = e0 + j;
                float hold = t ? sHold[e]
                               : (bits2f(curhi[hidx0 + j]) + bits2f(curlo[hidx0 + j]));
                float hnew = z * hold + (1.0f - z) * hc;
                sHold[e] = hnew;
                hn[j] = hnew;
                split_bf(hnew, nh[j], nl[j]);
            }
            if (t < TSTEPS - 1) {
                unsigned int hiw = (unsigned int)nh[0] | ((unsigned int)nh[1] << 16);
                unsigned int low = (unsigned int)nl[0] | ((unsigned int)nl[1] << 16);
                __hip_atomic_store((unsigned int*)&dsthi[hidx0], hiw,
                                   __ATOMIC_RELAXED, __HIP_MEMORY_SCOPE_AGENT);
                __hip_atomic_store((unsigned int*)&dstlo[hidx0], low,
                                   __ATOMIC_RELAXED, __HIP_MEMORY_SCOPE_AGENT);
            }
            const size_t o1 = (size_t)b * (TSTEPS * H) + (size_t)t * H + i0;
            if (isbf) {
                outb[o1]     = __float2bfloat16(hn[0]);
                outb[o1 + 1] = __float2bfloat16(hn[1]);
                if (t == TSTEPS - 1) {
                    outb[(size_t)BATCH * TSTEPS * H + hidx0]     = __float2bfloat16(hn[0]);
                    outb[(size_t)BATCH * TSTEPS * H + hidx0 + 1] = __float2bfloat16(hn[1]);
                }
            } else {
                outf[o1]     = hn[0];
                outf[o1 + 1] = hn[1];
                if (t == TSTEPS - 1) {
                    outf[(size_t)BATCH * TSTEPS * H + hidx0]     = hn[0];
                    outf[(size_t)BATCH * TSTEPS * H + hidx0 + 1] = hn[1];
                }
            }
        }

        // ---- per-bt-group arrival-array barrier (4 groups of 64 blocks) ----
        if (t < TSTEPS - 1) {
            asm volatile("s_waitcnt vmcnt(0)" ::: "memory");  // own h' stores acked
            __syncthreads();
            if (tid == 0) {
                __hip_atomic_store(&bar[bt * 64 + it], (unsigned int)(t + 1),
                                   __ATOMIC_RELAXED, __HIP_MEMORY_SCOPE_AGENT);
            }
            if (w == 0) {
                const unsigned int target = (unsigned int)(t + 1);
                for (;;) {
                    unsigned int v = __hip_atomic_load(&bar[bt * 64 + lane],
                                        __ATOMIC_RELAXED, __HIP_MEMORY_SCOPE_AGENT);
                    if (__all(v >= target)) break;
                    __builtin_amdgcn_s_sleep(1);
                }
            }
            __syncthreads();
        }
    }
}

extern "C" void kernel_launch(void* const* d_in, const int* in_sizes, int n_in,
                              void* d_out, int out_size, void* d_ws, size_t ws_size,
                              hipStream_t stream) {
    const void* cin  = d_in[0];
    const void* hs   = d_in[1];
    const void* Kw   = d_in[2];
    const void* Rw   = d_in[3];
    const void* bias = d_in[4];

    char* ws = (char*)d_ws;
    int* flag = (int*)ws;
    unsigned int* bar = (unsigned int*)(ws + BAR_OFF);
    __hip_bfloat16* pwh = (__hip_bfloat16*)(ws + PW_OFF);
    __hip_bfloat16* pwl = (__hip_bfloat16*)(ws + PWL_OFF);
    unsigned short* xhi  = (unsigned short*)(ws + XHI_OFF);
    unsigned short* xlo  = (unsigned short*)(ws + XLO_OFF);
    unsigned short* h0hi = (unsigned short*)(ws + H0HI_OFF);
    unsigned short* h0lo = (unsigned short*)(ws + H0LO_OFF);
    unsigned short* h1hi = (unsigned short*)(ws + H1HI_OFF);
    unsigned short* h1lo = (unsigned short*)(ws + H1LO_OFF);

    detect_dtype<<<1, 256, 0, stream>>>((const unsigned int*)Kw, flag);
    pack_w<<<3072, 256, 0, stream>>>(Kw, Rw, pwh, pwl, flag);
    init_bufs<<<512, 256, 0, stream>>>(cin, hs, xhi, xlo, h0hi, h0lo, bar, flag);

    const unsigned short* xhi_c = xhi;
    const unsigned short* xlo_c = xlo;
    const __hip_bfloat16* pwh_c = pwh;
    const __hip_bfloat16* pwl_c = pwl;
    const int* flag_c = flag;
    void* kargs[] = {
        (void*)&xhi_c, (void*)&xlo_c,
        (void*)&h0hi, (void*)&h0lo, (void*)&h1hi, (void*)&h1lo,
        (void*)&pwh_c, (void*)&pwl_c,
        (void*)&bias, (void*)&d_out, (void*)&bar, (void*)&flag_c
    };
    hipLaunchCooperativeKernel((void*)gru_persistent, dim3(256), dim3(NTHR),
                               kargs, 0, stream);
}